// Round 11
// baseline (180.356 us; speedup 1.0000x reference)
//
#include <hip/hip_runtime.h>
#include <hip/hip_bf16.h>

// CCAM (fp32 in/out): x (16,1024,64,64), martx (4096,64).
// rows = B*C = 16384, N = 4096 spatial, KDIM = 64.
// energy[r][k] = sum_n x[r][n] * M[n][k]           (GEMM1, K=4096)
// att = softmax(alpha * (rowmax(energy) - energy))  (64-wide)
// out[r][n] = gamma * sum_k att[r][k]*M[n][k] + x[r][n]
//
// Round-11: tracked-dep redesign of the round-6 winner:
//   - reg-staging (global->reg->cvt->ds_write bf16): all loads compiler-
//     tracked -> precise counted waits, no manual vmcnt, no untracked-DMA
//     hazards; raw s_barrier never drains vmcnt
//   - bf16 LDS x-buffers (3 x 8.4 KB, stride 528 B) -> 34.8 KB block LDS
//     -> 4 blocks/CU (32 waves/CU, 2x round 6's TLP)
//   - inner loop: 1 ds_read_b128 + 4 MFMA, ONE barrier per chunk
//   - phase 3: zero LDS, D-layout direct stores, xv dbuf + B3 prefetch

using frag_ab = __attribute__((ext_vector_type(8))) short;   // 8 bf16 = 4 VGPR
using f32x4   = __attribute__((ext_vector_type(4))) float;   // MFMA C/D

#define MFMA16(a, b, c) __builtin_amdgcn_mfma_f32_16x16x32_bf16((a), (b), (c), 0, 0, 0)
#define SBAR() __builtin_amdgcn_sched_barrier(0)

static __device__ __forceinline__ unsigned short f2bf_bits(float f) {
    __hip_bfloat16 h = __float2bfloat16(f);
    return *reinterpret_cast<const unsigned short*>(&h);
}
static __device__ __forceinline__ frag_ab load_frag(const __hip_bfloat16* p) {
    return *reinterpret_cast<const frag_ab*>(p);
}
static __device__ __forceinline__ frag_ab cvt2(float4 a, float4 b) {
    frag_ab r;
    r[0] = (short)f2bf_bits(a.x); r[1] = (short)f2bf_bits(a.y);
    r[2] = (short)f2bf_bits(a.z); r[3] = (short)f2bf_bits(a.w);
    r[4] = (short)f2bf_bits(b.x); r[5] = (short)f2bf_bits(b.y);
    r[6] = (short)f2bf_bits(b.z); r[7] = (short)f2bf_bits(b.w);
    return r;
}

// -------- kernel 0: build frag-linear B banks (unchanged, validated) --------
// MtF  (512 frags x 1 KB): frag f = slot*4+t, elem (lane,j) = M[32*slot+8g+j][16t+r15]
// MbfF (512 frags x 1 KB): frag f = nt*2+h,   elem (lane,j) = M[16nt+r15][32h+8g+j]
__global__ __launch_bounds__(256) void prep_frags(
        const float* __restrict__ M,
        __hip_bfloat16* __restrict__ MtF, __hip_bfloat16* __restrict__ MbfF) {
    const int w    = threadIdx.x >> 6;
    const int lane = threadIdx.x & 63;
    const int g    = lane >> 4;
    const int r15  = lane & 15;
    const int f    = blockIdx.x * 4 + w;    // 0..1023
    if (f < 512) {
        const int slot = f >> 2, t = f & 3;
        frag_ab fr;
#pragma unroll
        for (int j = 0; j < 8; ++j)
            fr[j] = (short)f2bf_bits(M[(size_t)(32 * slot + 8 * g + j) * 64 + 16 * t + r15]);
        *reinterpret_cast<frag_ab*>(MtF + ((size_t)f * 64 + lane) * 8) = fr;
    } else {
        const int f2 = f - 512;
        const float* src = M + (size_t)(16 * (f2 >> 1) + r15) * 64 + 32 * (f2 & 1) + 8 * g;
        float4 a = *reinterpret_cast<const float4*>(src);
        float4 b = *reinterpret_cast<const float4*>(src + 4);
        *reinterpret_cast<frag_ab*>(MbfF + ((size_t)f2 * 64 + lane) * 8) = cvt2(a, b);
    }
}

// -------- kernel 1: fused CCAM ----------------------------------------------
// LDS 34816 B: 3 bf16 x-buffers (16 rows x 264 bf16, 528 B stride) at
// 0/8448/16896; Ep[8][16][68] f32 overlays the whole region after the K-loop.
__global__ __launch_bounds__(512, 4) void ccam_main(
        const float* __restrict__ x,
        const __hip_bfloat16* __restrict__ MtF,
        const __hip_bfloat16* __restrict__ MbfF,
        const float* __restrict__ aphal,
        const float* __restrict__ gamma,
        float* __restrict__ out) {
    __shared__ __align__(16) char smem[34816];
    float (*Ep)[16][68] = (float(*)[16][68])smem;

    const int tid  = threadIdx.x;
    const int w    = tid >> 6;        // wave 0..7
    const int lane = tid & 63;
    const int g    = lane >> 4;
    const int r15  = lane & 15;
    const int rowbase = blockIdx.x * 16;

    const float alpha = aphal[0];
    const float gam   = gamma[0];

    // ===== Phase 1: energy; 16 chunks of 256 contraction cols =====
    // stage: wave w covers rows {2w, 2w+1}; lane -> row 2w+(lane>>5), 8 cols
    const int srow = 2 * w + (lane >> 5);
    const int scol = (lane & 31) * 8;
    const float* xsrc = x + (size_t)(rowbase + srow) * 4096 + scol;
    char* const  swp  = smem + srow * 528 + scol * 2;          // + buf*8448
    const char* const srp = smem + r15 * 528 + 64 * w + 16 * g; // + buf*8448

    f32x4 acc0 = {0.f, 0.f, 0.f, 0.f};
    f32x4 acc1 = acc0, acc2 = acc0, acc3 = acc0;
    {
        float4 xp[2][2];    // [chunk&1][half] — constant idx after full unroll
        frag_ab B[2][4];    // [chunk&1][t]

        // prologue: chunk0+chunk1 loads, B(0); write chunk0 -> buf0
        xp[0][0] = *reinterpret_cast<const float4*>(xsrc);
        xp[0][1] = *reinterpret_cast<const float4*>(xsrc + 4);
        xp[1][0] = *reinterpret_cast<const float4*>(xsrc + 256);
        xp[1][1] = *reinterpret_cast<const float4*>(xsrc + 256 + 4);
        {
            const __hip_bfloat16* bp = MtF + (((size_t)w * 4) * 64 + lane) * 8;
            B[0][0] = load_frag(bp);
            B[0][1] = load_frag(bp + 512);
            B[0][2] = load_frag(bp + 1024);
            B[0][3] = load_frag(bp + 1536);
        }
        SBAR();
        *reinterpret_cast<frag_ab*>(swp) = cvt2(xp[0][0], xp[0][1]);   // buf0
        asm volatile("s_waitcnt lgkmcnt(0)" ::: "memory");
        SBAR();
        __builtin_amdgcn_s_barrier();
        SBAR();

#pragma unroll
        for (int c = 0; c < 16; ++c) {
            // issue chunk c+2 x-loads into the freed slot
            if (c + 2 < 16) {
                xp[c & 1][0] = *reinterpret_cast<const float4*>(xsrc + (c + 2) * 256);
                xp[c & 1][1] = *reinterpret_cast<const float4*>(xsrc + (c + 2) * 256 + 4);
            }
            // prefetch B(c+1)
            if (c + 1 < 16) {
                const __hip_bfloat16* bp =
                    MtF + (((size_t)(8 * (c + 1) + w) * 4) * 64 + lane) * 8;
                B[(c + 1) & 1][0] = load_frag(bp);
                B[(c + 1) & 1][1] = load_frag(bp + 512);
                B[(c + 1) & 1][2] = load_frag(bp + 1024);
                B[(c + 1) & 1][3] = load_frag(bp + 1536);
            }
            SBAR();
            // compute chunk c (A from LDS bf16, no cvt on critical path)
            frag_ab A = *reinterpret_cast<const frag_ab*>(srp + (c % 3) * 8448);
            acc0 = MFMA16(A, B[c & 1][0], acc0);
            acc1 = MFMA16(A, B[c & 1][1], acc1);
            acc2 = MFMA16(A, B[c & 1][2], acc2);
            acc3 = MFMA16(A, B[c & 1][3], acc3);
            SBAR();
            // write chunk c+1 (compiler inserts the precise vmcnt for xp)
            if (c + 1 < 16)
                *reinterpret_cast<frag_ab*>(swp + ((c + 1) % 3) * 8448) =
                    cvt2(xp[(c + 1) & 1][0], xp[(c + 1) & 1][1]);
            asm volatile("s_waitcnt lgkmcnt(0)" ::: "memory");
            SBAR();
            __builtin_amdgcn_s_barrier();
            SBAR();
        }
    }
    __syncthreads();   // x-buffers die; Ep region becomes live

    // ===== Phase 1b: partials -> Ep =====
    // D layout: col = r15 (kdim-in-16-tile), row = 4g+reg (channel)
#pragma unroll
    for (int r = 0; r < 4; ++r) {
        Ep[w][4 * g + r][ 0 + r15] = acc0[r];
        Ep[w][4 * g + r][16 + r15] = acc1[r];
        Ep[w][4 * g + r][32 + r15] = acc2[r];
        Ep[w][4 * g + r][48 + r15] = acc3[r];
    }
    __syncthreads();

    // ===== Phase 2: softmax (every wave redundantly; lands in A-frag layout) =====
    float e[16];
#pragma unroll
    for (int j = 0; j < 16; ++j) e[j] = 0.f;
#pragma unroll
    for (int p = 0; p < 8; ++p) {
        float4 lo  = *reinterpret_cast<const float4*>(&Ep[p][r15][8 * g]);
        float4 lo2 = *reinterpret_cast<const float4*>(&Ep[p][r15][8 * g + 4]);
        float4 hi  = *reinterpret_cast<const float4*>(&Ep[p][r15][32 + 8 * g]);
        float4 hi2 = *reinterpret_cast<const float4*>(&Ep[p][r15][32 + 8 * g + 4]);
        e[0] += lo.x;  e[1] += lo.y;  e[2]  += lo.z;  e[3]  += lo.w;
        e[4] += lo2.x; e[5] += lo2.y; e[6]  += lo2.z; e[7]  += lo2.w;
        e[8] += hi.x;  e[9] += hi.y;  e[10] += hi.z;  e[11] += hi.w;
        e[12] += hi2.x; e[13] += hi2.y; e[14] += hi2.z; e[15] += hi2.w;
    }
    float m = e[0];
#pragma unroll
    for (int j = 1; j < 16; ++j) m = fmaxf(m, e[j]);
    m = fmaxf(m, __shfl_xor(m, 16, 64));
    m = fmaxf(m, __shfl_xor(m, 32, 64));
#pragma unroll
    for (int j = 0; j < 16; ++j) e[j] = alpha * (m - e[j]);
    float vm = e[0];
#pragma unroll
    for (int j = 1; j < 16; ++j) vm = fmaxf(vm, e[j]);
    vm = fmaxf(vm, __shfl_xor(vm, 16, 64));
    vm = fmaxf(vm, __shfl_xor(vm, 32, 64));
    float s = 0.f;
#pragma unroll
    for (int j = 0; j < 16; ++j) { e[j] = __expf(e[j] - vm); s += e[j]; }
    s += __shfl_xor(s, 16, 64);
    s += __shfl_xor(s, 32, 64);
    const float sc = gam / s;                 // fold gamma into attention
    frag_ab A0, A1;   // row = r15 (channel), k = 8g+j (A0) / 32+8g+j (A1)
#pragma unroll
    for (int j = 0; j < 8; ++j) {
        A0[j] = (short)f2bf_bits(e[j] * sc);
        A1[j] = (short)f2bf_bits(e[8 + j] * sc);
    }
    // phase 3 uses no LDS -> no further barriers needed

    // ===== Phase 3: out = (gam*att) @ M^T + x ; wave-private, LDS-free =====
    // wave w covers n in [512w, 512w+512): 8 grps of 64 cols.
    // D-layout direct: element (t,reg) -> out[rowbase+4g+reg][nbase+16t+r15]
    const int nb0 = 512 * w;
    const float* xbase = x   + (size_t)(rowbase + 4 * g) * 4096 + r15;
    float*       obase = out + (size_t)(rowbase + 4 * g) * 4096 + r15;

    float  xv[2][16];   // [grp&1][4t+reg] — constant idx after full unroll
    frag_ab B3[8];      // [2t+h], single-buffered, prefetched 1 grp ahead

    // prologue: B3(grp0), xv(grp0), xv(grp1)
    {
        const __hip_bfloat16* bb = MbfF + (((size_t)(32 * w) * 2) * 64 + lane) * 8;
#pragma unroll
        for (int k = 0; k < 8; ++k) B3[k] = load_frag(bb + k * 512);
    }
#pragma unroll
    for (int t = 0; t < 4; ++t)
#pragma unroll
        for (int r = 0; r < 4; ++r)
            xv[0][4 * t + r] = xbase[(size_t)r * 4096 + nb0 + 16 * t];
#pragma unroll
    for (int t = 0; t < 4; ++t)
#pragma unroll
        for (int r = 0; r < 4; ++r)
            xv[1][4 * t + r] = xbase[(size_t)r * 4096 + nb0 + 64 + 16 * t];
    SBAR();

#pragma unroll
    for (int grp = 0; grp < 8; ++grp) {
        const int nbase = nb0 + grp * 64;
        f32x4 d0 = {0.f, 0.f, 0.f, 0.f};
        f32x4 d1 = d0, d2 = d0, d3 = d0;
        d0 = MFMA16(A0, B3[0], d0); d0 = MFMA16(A1, B3[1], d0);
        d1 = MFMA16(A0, B3[2], d1); d1 = MFMA16(A1, B3[3], d1);
        d2 = MFMA16(A0, B3[4], d2); d2 = MFMA16(A1, B3[5], d2);
        d3 = MFMA16(A0, B3[6], d3); d3 = MFMA16(A1, B3[7], d3);
#pragma unroll
        for (int r = 0; r < 4; ++r) {
            obase[(size_t)r * 4096 + nbase +  0] = d0[r] + xv[grp & 1][ 0 + r];
            obase[(size_t)r * 4096 + nbase + 16] = d1[r] + xv[grp & 1][ 4 + r];
            obase[(size_t)r * 4096 + nbase + 32] = d2[r] + xv[grp & 1][ 8 + r];
            obase[(size_t)r * 4096 + nbase + 48] = d3[r] + xv[grp & 1][12 + r];
        }
        SBAR();
        // prefetch: B3(grp+1) then xv(grp+2) (issue order fixes wait counts)
        if (grp + 1 < 8) {
            const __hip_bfloat16* bb =
                MbfF + (((size_t)(32 * w + 4 * (grp + 1)) * 2) * 64 + lane) * 8;
#pragma unroll
            for (int k = 0; k < 8; ++k) B3[k] = load_frag(bb + k * 512);
        }
        if (grp + 2 < 8) {
#pragma unroll
            for (int t = 0; t < 4; ++t)
#pragma unroll
                for (int r = 0; r < 4; ++r)
                    xv[grp & 1][4 * t + r] =
                        xbase[(size_t)r * 4096 + nb0 + (grp + 2) * 64 + 16 * t];
        }
        SBAR();
    }
}

extern "C" void kernel_launch(void* const* d_in, const int* in_sizes, int n_in,
                              void* d_out, int out_size, void* d_ws, size_t ws_size,
                              hipStream_t stream) {
    const float* x     = (const float*)d_in[0];
    const float* M     = (const float*)d_in[1];
    const float* aphal = (const float*)d_in[2];
    const float* gamma = (const float*)d_in[3];
    __hip_bfloat16* MtF  = (__hip_bfloat16*)d_ws;                  // 512 KB
    __hip_bfloat16* MbfF = (__hip_bfloat16*)d_ws + 64 * 4096;      // 512 KB

    hipLaunchKernelGGL(prep_frags, dim3(256), dim3(256), 0, stream, M, MtF, MbfF);
    hipLaunchKernelGGL(ccam_main, dim3(1024), dim3(512), 0, stream,
                       x, MtF, MbfF, aphal, gamma, (float*)d_out);
}

// Round 12
// 165.376 us; speedup vs baseline: 1.0906x; 1.0906x over previous
//
#include <hip/hip_runtime.h>
#include <hip/hip_bf16.h>

// CCAM (fp32 in/out): x (16,1024,64,64), martx (4096,64).
// rows = B*C = 16384, N = 4096 spatial, KDIM = 64.
// energy[r][k] = sum_n x[r][n] * M[n][k]           (GEMM1, K=4096)
// att = softmax(alpha * (rowmax(energy) - energy))  (64-wide)
// out[r][n] = gamma * sum_k att[r][k]*M[n][k] + x[r][n]
//
// Round-12: round-10 skeleton, ONE change — phase-3 in-place update is now
// all-lane. With 8 rows, D rows 8-15 duplicate rows 0-7, so lanes g>=2 hold
// exactly D[4(g-2)+reg][{32,48}+r15]: g<2 lanes update tiles {0,1}, g>=2
// lanes update tiles {2,3}. 64/64 lanes active, 8 RMW elems/lane (was 32
// scalar RMWs on half the lanes) -> ~4x less serial LDS latency.

using frag_ab = __attribute__((ext_vector_type(8))) short;   // 8 bf16
using f32x4   = __attribute__((ext_vector_type(4))) float;   // MFMA C/D

#define MFMA16(a, b, c) __builtin_amdgcn_mfma_f32_16x16x32_bf16((a), (b), (c), 0, 0, 0)

static __device__ __forceinline__ unsigned short f2bf_bits(float f) {
    __hip_bfloat16 h = __float2bfloat16(f);
    return *reinterpret_cast<const unsigned short*>(&h);
}
static __device__ __forceinline__ float bf2f(unsigned short u) {
    return __uint_as_float(((unsigned)u) << 16);
}
static __device__ __forceinline__ frag_ab load_frag(const __hip_bfloat16* p) {
    return *reinterpret_cast<const frag_ab*>(p);
}
static __device__ __forceinline__ frag_ab cvt2(float4 a, float4 b) {
    frag_ab r;
    r[0] = (short)f2bf_bits(a.x); r[1] = (short)f2bf_bits(a.y);
    r[2] = (short)f2bf_bits(a.z); r[3] = (short)f2bf_bits(a.w);
    r[4] = (short)f2bf_bits(b.x); r[5] = (short)f2bf_bits(b.y);
    r[6] = (short)f2bf_bits(b.z); r[7] = (short)f2bf_bits(b.w);
    return r;
}

// -------- kernel 0: build frag-linear B banks (unchanged, validated) --------
// MtF  (512 frags x 1 KB): frag f = slot*4+t, elem (lane,j) = M[32*slot+8g+j][16t+r15]
// MbfF (512 frags x 1 KB): frag f = nt*2+h,   elem (lane,j) = M[16nt+r15][32h+8g+j]
__global__ __launch_bounds__(256) void prep_frags(
        const float* __restrict__ M,
        __hip_bfloat16* __restrict__ MtF, __hip_bfloat16* __restrict__ MbfF) {
    const int w    = threadIdx.x >> 6;
    const int lane = threadIdx.x & 63;
    const int g    = lane >> 4;
    const int r15  = lane & 15;
    const int f    = blockIdx.x * 4 + w;    // 0..1023
    if (f < 512) {
        const int slot = f >> 2, t = f & 3;
        frag_ab fr;
#pragma unroll
        for (int j = 0; j < 8; ++j)
            fr[j] = (short)f2bf_bits(M[(size_t)(32 * slot + 8 * g + j) * 64 + 16 * t + r15]);
        *reinterpret_cast<frag_ab*>(MtF + ((size_t)f * 64 + lane) * 8) = fr;
    } else {
        const int f2 = f - 512;
        const float* src = M + (size_t)(16 * (f2 >> 1) + r15) * 64 + 32 * (f2 & 1) + 8 * g;
        float4 a = *reinterpret_cast<const float4*>(src);
        float4 b = *reinterpret_cast<const float4*>(src + 4);
        *reinterpret_cast<frag_ab*>(MbfF + ((size_t)f2 * 64 + lane) * 8) = cvt2(a, b);
    }
}

// -------- kernel 1: fused CCAM, 8-row blocks, sequential streams ------------
// LDS 69760 B: x image 8 rows x 8208 B (bf16, stride 4104 elems) = 65664;
//              Ep[4][2][8][16] f32 = 4096 at offset 65664.  2 blocks/CU.
__global__ __launch_bounds__(512, 2) void ccam_fused(
        const float* __restrict__ x,
        const __hip_bfloat16* __restrict__ MtF,
        const __hip_bfloat16* __restrict__ MbfF,
        const float* __restrict__ aphal,
        const float* __restrict__ gamma,
        float* __restrict__ out) {
    __shared__ __align__(16) char smem[69760];
    float* Ep = (float*)(smem + 65664);    // [t][h][row][16] floats

    const int tid  = threadIdx.x;
    const int w    = tid >> 6;             // wave 0..7
    const int lane = tid & 63;
    const int g    = lane >> 4;
    const int r15  = lane & 15;
    const int r7   = r15 & 7;
    const int rowbase = blockIdx.x * 8;

    const float alpha = aphal[0];
    const float gam   = gamma[0];

    // ===== stage: wave w reads row w sequentially, bf16 into LDS =====
    {
        const float* xr = x + (size_t)(rowbase + w) * 4096;
        char* dst = smem + w * 8208;
#pragma unroll
        for (int rnd = 0; rnd < 2; ++rnd) {
            float4 v[8];
#pragma unroll
            for (int i = 0; i < 8; ++i)
                v[i] = *reinterpret_cast<const float4*>(xr + rnd * 2048 + i * 256 + 4 * lane);
#pragma unroll
            for (int i = 0; i < 8; ++i) {
                ushort4 u;
                u.x = f2bf_bits(v[i].x); u.y = f2bf_bits(v[i].y);
                u.z = f2bf_bits(v[i].z); u.w = f2bf_bits(v[i].w);
                *reinterpret_cast<ushort4*>(dst + (rnd * 2048 + i * 256 + 4 * lane) * 2) = u;
            }
        }
    }
    __syncthreads();

    // ===== phase 1: energy from LDS; wave = (kdim-tile t1, K-half h1) =====
    const int t1 = w >> 1;
    const int h1 = w & 1;
    f32x4 acc = {0.f, 0.f, 0.f, 0.f};
    {
        const char* arow = smem + r7 * 8208;
        frag_ab Bc = load_frag(MtF + (((size_t)(64 * h1) * 4 + t1) * 64 + lane) * 8);
#pragma unroll 4
        for (int s = 0; s < 64; ++s) {
            frag_ab Bn = Bc;
            if (s < 63)
                Bn = load_frag(MtF + (((size_t)(64 * h1 + s + 1) * 4 + t1) * 64 + lane) * 8);
            frag_ab A = *reinterpret_cast<const frag_ab*>(
                arow + (h1 * 2048 + 32 * s + 8 * g) * 2);
            acc = MFMA16(A, Bc, acc);
            Bc = Bn;
        }
    }
    // Ep: rows 0..7 live in lanes g<2 (D row = 4g+reg)
    if (g < 2) {
#pragma unroll
        for (int reg = 0; reg < 4; ++reg)
            Ep[(((t1 * 2 + h1) * 8) + 4 * g + reg) * 16 + r15] = acc[reg];
    }
    __syncthreads();

    // ===== phase 2: softmax; lane builds its own phase-3 A-frag slice =====
    // lane (g,r15): row r7; k = 8g+j (A0) and 32+8g+j (A1)
    float elo[8], ehi[8];
    {
        const int t0  = g >> 1;
        const int off = 8 * (g & 1);
        const float* e0 = Ep + ((t0 * 2 + 0) * 8 + r7) * 16 + off;
        const float* e1 = Ep + ((t0 * 2 + 1) * 8 + r7) * 16 + off;
        const float* e2 = Ep + (((t0 + 2) * 2 + 0) * 8 + r7) * 16 + off;
        const float* e3 = Ep + (((t0 + 2) * 2 + 1) * 8 + r7) * 16 + off;
        float4 a0 = *reinterpret_cast<const float4*>(e0);
        float4 a1 = *reinterpret_cast<const float4*>(e0 + 4);
        float4 b0 = *reinterpret_cast<const float4*>(e1);
        float4 b1 = *reinterpret_cast<const float4*>(e1 + 4);
        elo[0] = a0.x + b0.x; elo[1] = a0.y + b0.y; elo[2] = a0.z + b0.z; elo[3] = a0.w + b0.w;
        elo[4] = a1.x + b1.x; elo[5] = a1.y + b1.y; elo[6] = a1.z + b1.z; elo[7] = a1.w + b1.w;
        float4 c0 = *reinterpret_cast<const float4*>(e2);
        float4 c1 = *reinterpret_cast<const float4*>(e2 + 4);
        float4 d0 = *reinterpret_cast<const float4*>(e3);
        float4 d1 = *reinterpret_cast<const float4*>(e3 + 4);
        ehi[0] = c0.x + d0.x; ehi[1] = c0.y + d0.y; ehi[2] = c0.z + d0.z; ehi[3] = c0.w + d0.w;
        ehi[4] = c1.x + d1.x; ehi[5] = c1.y + d1.y; ehi[6] = c1.z + d1.z; ehi[7] = c1.w + d1.w;
    }
    float m = elo[0];
#pragma unroll
    for (int j = 1; j < 8; ++j) m = fmaxf(m, elo[j]);
#pragma unroll
    for (int j = 0; j < 8; ++j) m = fmaxf(m, ehi[j]);
    m = fmaxf(m, __shfl_xor(m, 8, 64));
    m = fmaxf(m, __shfl_xor(m, 16, 64));
    m = fmaxf(m, __shfl_xor(m, 32, 64));
#pragma unroll
    for (int j = 0; j < 8; ++j) { elo[j] = alpha * (m - elo[j]); ehi[j] = alpha * (m - ehi[j]); }
    float vm = elo[0];
#pragma unroll
    for (int j = 1; j < 8; ++j) vm = fmaxf(vm, elo[j]);
#pragma unroll
    for (int j = 0; j < 8; ++j) vm = fmaxf(vm, ehi[j]);
    vm = fmaxf(vm, __shfl_xor(vm, 8, 64));
    vm = fmaxf(vm, __shfl_xor(vm, 16, 64));
    vm = fmaxf(vm, __shfl_xor(vm, 32, 64));
    float s = 0.f;
#pragma unroll
    for (int j = 0; j < 8; ++j) { elo[j] = __expf(elo[j] - vm); s += elo[j]; }
#pragma unroll
    for (int j = 0; j < 8; ++j) { ehi[j] = __expf(ehi[j] - vm); s += ehi[j]; }
    s += __shfl_xor(s, 8, 64);
    s += __shfl_xor(s, 16, 64);
    s += __shfl_xor(s, 32, 64);
    const float sc = gam / s;               // fold gamma into attention
    frag_ab A0, A1;
#pragma unroll
    for (int j = 0; j < 8; ++j) {
        A0[j] = (short)f2bf_bits(elo[j] * sc);
        A1[j] = (short)f2bf_bits(ehi[j] * sc);
    }

    // ===== phase 3: out into LDS image in place; wave w owns cols [512w,+512) =====
    // ALL-LANE update via D duplication: g<2 -> tiles {0,1} (d0,d1), rows 4g+reg;
    // g>=2 -> tiles {2,3} (d2,d3), rows 4(g-2)+reg (same numeric rows 4(g&1)+reg).
    const int urow0 = 4 * (g & 1);          // 0 or 4
    const int coff  = (g < 2) ? 0 : 32;     // tile-pair column offset
#pragma unroll 1
    for (int gi = 0; gi < 8; ++gi) {
        const int grp = 8 * w + gi;
        frag_ab B[4][2];
#pragma unroll
        for (int t = 0; t < 4; ++t)
#pragma unroll
            for (int h = 0; h < 2; ++h)
                B[t][h] = load_frag(MbfF + (((size_t)(4 * grp + t) * 2 + h) * 64 + lane) * 8);
        f32x4 d0 = {0.f, 0.f, 0.f, 0.f};
        f32x4 d1 = d0, d2 = d0, d3 = d0;
        d0 = MFMA16(A0, B[0][0], d0); d0 = MFMA16(A1, B[0][1], d0);
        d1 = MFMA16(A0, B[1][0], d1); d1 = MFMA16(A1, B[1][1], d1);
        d2 = MFMA16(A0, B[2][0], d2); d2 = MFMA16(A1, B[2][1], d2);
        d3 = MFMA16(A0, B[3][0], d3); d3 = MFMA16(A1, B[3][1], d3);
        // per-lane select of the tile-pair this lane owns (no divergence)
        f32x4 va, vb;
#pragma unroll
        for (int reg = 0; reg < 4; ++reg) {
            va[reg] = (g < 2) ? d0[reg] : d2[reg];
            vb[reg] = (g < 2) ? d1[reg] : d3[reg];
        }
        const int colbase = grp * 64 + coff + r15;
#pragma unroll
        for (int reg = 0; reg < 4; ++reg) {
            unsigned short* pa =
                (unsigned short*)(smem + (urow0 + reg) * 8208) + colbase;
            unsigned short* pb = pa + 16;
            *pa = f2bf_bits(va[reg] + bf2f(*pa));
            *pb = f2bf_bits(vb[reg] + bf2f(*pb));
        }
    }
    __syncthreads();

    // ===== store: wave w streams row w out sequentially =====
    {
        const char* srow = smem + w * 8208;
        float* orow = out + (size_t)(rowbase + w) * 4096;
#pragma unroll
        for (int i = 0; i < 16; ++i) {
            const int col = 256 * i + 4 * lane;
            ushort4 u = *reinterpret_cast<const ushort4*>(srow + col * 2);
            float4 v;
            v.x = bf2f(u.x); v.y = bf2f(u.y); v.z = bf2f(u.z); v.w = bf2f(u.w);
            *reinterpret_cast<float4*>(orow + col) = v;
        }
    }
}

extern "C" void kernel_launch(void* const* d_in, const int* in_sizes, int n_in,
                              void* d_out, int out_size, void* d_ws, size_t ws_size,
                              hipStream_t stream) {
    const float* x     = (const float*)d_in[0];
    const float* M     = (const float*)d_in[1];
    const float* aphal = (const float*)d_in[2];
    const float* gamma = (const float*)d_in[3];
    __hip_bfloat16* MtF  = (__hip_bfloat16*)d_ws;                  // 512 KB
    __hip_bfloat16* MbfF = (__hip_bfloat16*)d_ws + 64 * 4096;      // 512 KB

    hipLaunchKernelGGL(prep_frags, dim3(256), dim3(256), 0, stream, M, MtF, MbfF);
    hipLaunchKernelGGL(ccam_fused, dim3(2048), dim3(512), 0, stream,
                       x, MtF, MbfF, aphal, gamma, (float*)d_out);
}